// Round 4
// baseline (96.368 us; speedup 1.0000x reference)
//
#include <hip/hip_runtime.h>

// Problem constants (fixed by reference)
#define BATCH 2
#define NPTS  2048
#define CIN   64
#define COUT  128
#define GD    14                 // padded grid dim (12 + 2 halo)
#define GD2   (GD*GD)            // 196
#define NCELL (GD*GD*GD)         // 2744
#define M     (BATCH*NPTS)       // 4096
#define VOXF  (BATCH*NCELL*CIN)  // 351232 floats
#define MCELL (BATCH*1728)       // 3456 dense-conv output rows

typedef __bf16 bf16x8 __attribute__((ext_vector_type(8)));
typedef float  f32x4  __attribute__((ext_vector_type(4)));
typedef unsigned short us8 __attribute__((ext_vector_type(8)));

__device__ __forceinline__ unsigned short f2bf(float f) {
    unsigned u = __builtin_bit_cast(unsigned, f);
    return (unsigned short)((u + 0x7FFFu + ((u >> 16) & 1u)) >> 16);  // RNE
}

// Kernel 1 (fused prep):
//  blocks 0..17   : transpose weight (3,3,3,64,128) fp32 -> bf16 wT2[p=oi*3+oj][n=128][kk=ok*64+k=192]
//  blocks 18..1041: scatter-add features into zeroed fp32 voxgrid (cell computed inline)
__global__ __launch_bounds__(256) void k_prep(const float* __restrict__ points,
                                              const float* __restrict__ features,
                                              const float* __restrict__ weight,
                                              float* __restrict__ voxgrid,
                                              unsigned short* __restrict__ wT2) {
    const int t = threadIdx.x;
    if (blockIdx.x < 18) {
        const int p  = blockIdx.x >> 1;   // (oi,oj) pair 0..8
        const int nh = blockIdx.x & 1;    // n half: 64 couts
        __shared__ unsigned short lds[64*194];   // [nn][kk], stride 194 (97 dwords, odd)
        // load coalesced over n, convert
        #pragma unroll
        for (int i = 0; i < 48; ++i) {    // 12288 = 64n x 192k elements
            const int s  = t + i*256;
            const int nn = s & 63;
            const int kk = s >> 6;        // 0..191
            const int ok = kk >> 6, k = kk & 63;
            lds[nn*194 + kk] = f2bf(weight[(p*3 + ok)*8192 + k*128 + nh*64 + nn]);
        }
        __syncthreads();
        // store coalesced over kk
        #pragma unroll
        for (int i = 0; i < 48; ++i) {
            const int s  = t + i*256;
            const int nn = s / 192;
            const int kk = s - nn*192;
            wT2[(size_t)(p*128 + nh*64 + nn)*192 + kk] = lds[nn*194 + kk];
        }
    } else {
        const int idx = (blockIdx.x - 18)*256 + t;   // [0, M*CIN)
        const int g   = idx >> 6;
        const int cin = idx & 63;
        const int vx = (int)points[g*3 + 0];
        const int vy = (int)points[g*3 + 1];
        const int vz = (int)points[g*3 + 2];
        const int cell = (vx + 1)*GD2 + (vy + 1)*GD + (vz + 1);
        atomicAdd(&voxgrid[((size_t)(g >> 11)*NCELL + cell)*CIN + cin], features[idx]);
    }
}

// Kernel 2: convert fp32 voxgrid -> bf16 (whole padded grid, halo stays zero).
__global__ __launch_bounds__(256) void k_pack(const float* __restrict__ voxgrid,
                                              unsigned short* __restrict__ voxbf) {
    const int idx = blockIdx.x * 256 + threadIdx.x;   // [0, VOXF/8)
    if (idx >= VOXF/8) return;
    const float4 v0 = ((const float4*)voxgrid)[idx*2 + 0];
    const float4 v1 = ((const float4*)voxgrid)[idx*2 + 1];
    us8 p;
    p[0] = f2bf(v0.x); p[1] = f2bf(v0.y); p[2] = f2bf(v0.z); p[3] = f2bf(v0.w);
    p[4] = f2bf(v1.x); p[5] = f2bf(v1.y); p[6] = f2bf(v1.z); p[7] = f2bf(v1.w);
    *(us8*)(voxbf + idx*8) = p;
}

// Kernel 3: dense MFMA conv over the 12^3 grid.
// outgrid[b][ci][n] = bias[n] + sum_p sum_kk voxbf[(vpad(ci)+delta(p))*64 .. +192][kk] * wT2[p][n][kk]
// Wave = 16 cells x 16 couts; block = 4 waves (64 couts); grid (216 m-tiles, 2 n-halves).
__global__ __launch_bounds__(256) void k_conv(const unsigned short* __restrict__ voxbf,
                                              const unsigned short* __restrict__ wT2,
                                              const float* __restrict__ bias,
                                              float* __restrict__ outgrid) {
    // delta(p)*64 for p = oi*3+oj, base at ok=-1 (contiguous 192-ch span)
    static constexpr int DOFF[9] = { -13504, -12608, -11712,
                                       -960,    -64,    832,
                                      11584,  12480,  13376 };

    const int t    = threadIdx.x;
    const int l    = t & 63;
    const int w    = t >> 6;
    const int q    = l >> 4;          // lane quad: k-offset q*8
    const int col  = l & 15;          // A-row (m) and B-col (n) index
    const int mblk = blockIdx.x;      // 0..215
    const int b    = (mblk >= 108);
    const int ci0  = (mblk - b*108) * 16;
    const int n0   = blockIdx.y*64 + w*16;

    // this lane's A row: cell ci0+col, padded address
    const int ci = ci0 + col;
    const int cx = ci / 144, cy = (ci / 12) % 12, cz = ci % 12;
    const int v  = (cx + 1)*GD2 + (cy + 1)*GD + (cz + 1);
    const unsigned short* aptr = voxbf + (size_t)(b*NCELL + v)*64 + q*8;
    const unsigned short* bptr = wT2 + (size_t)(n0 + col)*192 + q*8;

    f32x4 acc = {0.f, 0.f, 0.f, 0.f};

    // 54 k-steps (9 panels x 6 steps of 32), depth-4 register pipeline
    us8 Ab[4], Bb[4];
    #pragma unroll
    for (int st = 0; st < 4; ++st) {
        const int p = st / 6, s = st % 6;
        Ab[st] = *(const us8*)(aptr + DOFF[p] + s*32);
        Bb[st] = *(const us8*)(bptr + p*24576 + s*32);
    }
    #pragma unroll
    for (int st = 0; st < 54; ++st) {
        const int sl = st & 3;
        const us8 a = Ab[sl], bb = Bb[sl];
        if (st + 4 < 54) {
            const int p = (st + 4) / 6, s = (st + 4) % 6;
            Ab[sl] = *(const us8*)(aptr + DOFF[p] + s*32);
            Bb[sl] = *(const us8*)(bptr + p*24576 + s*32);
        }
        acc = __builtin_amdgcn_mfma_f32_16x16x32_bf16(
                  __builtin_bit_cast(bf16x8, a), __builtin_bit_cast(bf16x8, bb), acc, 0, 0, 0);
    }

    // C/D layout: n = col, m-row = q*4 + r; bias fused here
    const float bs = bias[n0 + col];
    #pragma unroll
    for (int r = 0; r < 4; ++r) {
        outgrid[(size_t)(mblk*16 + q*4 + r)*128 + n0 + col] = acc[r] + bs;
    }
}

// Kernel 4: per-point gather: out[g][:] = outgrid[b*1728 + ci(g)][:]  (bias already added)
__global__ __launch_bounds__(256) void k_gather(const float* __restrict__ points,
                                                const float* __restrict__ outgrid,
                                                float* __restrict__ out) {
    const int idx = blockIdx.x * 256 + threadIdx.x;   // [0, M*32)
    const int g   = idx >> 5;
    const int c4  = idx & 31;
    const int vx = (int)points[g*3 + 0];
    const int vy = (int)points[g*3 + 1];
    const int vz = (int)points[g*3 + 2];
    const int ci = vx*144 + vy*12 + vz;
    const int mg = (g >> 11)*1728 + ci;
    ((float4*)out)[(size_t)g*32 + c4] = ((const float4*)outgrid)[(size_t)mg*32 + c4];
}

extern "C" void kernel_launch(void* const* d_in, const int* in_sizes, int n_in,
                              void* d_out, int out_size, void* d_ws, size_t ws_size,
                              hipStream_t stream) {
    (void)in_sizes; (void)n_in; (void)out_size; (void)ws_size;
    const float* points   = (const float*)d_in[0];  // (2,2048,3)
    const float* features = (const float*)d_in[1];  // (2,2048,64)
    const float* weight   = (const float*)d_in[2];  // (3,3,3,64,128)
    const float* bias     = (const float*)d_in[3];  // (128,)
    float* out = (float*)d_out;                     // (2,2048,128)

    char* ws = (char*)d_ws;
    float*          voxgrid = (float*)ws;                              // 1,404,928 B
    unsigned short* voxbf   = (unsigned short*)(ws + 1404928);         //   702,464 B
    unsigned short* wT2     = (unsigned short*)(ws + 1404928 + 702464);//   442,368 B
    float*          outgrid = (float*)(ws + 1404928 + 702464 + 442368);// 1,769,472 B

    hipMemsetAsync(voxgrid, 0, (size_t)VOXF*4, stream);
    k_prep<<<18 + (M*CIN)/256, 256, 0, stream>>>(points, features, weight, voxgrid, wT2);
    k_pack<<<(VOXF/8 + 255)/256, 256, 0, stream>>>(voxgrid, voxbf);
    dim3 cgrid(MCELL/16, 2, 1);
    k_conv<<<cgrid, 256, 0, stream>>>(voxbf, wT2, bias, outgrid);
    k_gather<<<(M*32)/256, 256, 0, stream>>>(points, outgrid, out);
}